// Round 3
// baseline (220.849 us; speedup 1.0000x reference)
//
#include <hip/hip_runtime.h>
#include <hip/hip_bf16.h>
#include <stdint.h>

#define N_   64
#define L_   1024
#define D_   512
#define S_   127
#define OUT_ 300
#define NT_  20            // col-tiles of 16 -> 320 padded cols
#define OUTP (NT_*16)      // 320
#define EPS_ 1e-5f
#define M_TOTAL (N_*S_)    // 8128
#define NBLK (M_TOTAL/16)  // 508 waves, one per 16-row strip

typedef __attribute__((ext_vector_type(4))) float  float4v;
typedef __attribute__((ext_vector_type(8))) __bf16 bf16x8;

// --- w_lin f32 -> bf16, packed in MFMA B-fragment order ---
// elem layout: [t(20)][kt(8)][ks(2)][quad(4)][ln16(16)][j(8)]
// so in the GEMM, lane's B-frag for (t,kt,ks) sits at (t*1024+kt*128+ks*64+lane)*8
// -> wave load = 64 lanes x 16B fully contiguous (1 KB).
__global__ void conv_w_pack(const float* __restrict__ w, __bf16* __restrict__ wpk) {
    int idx = blockIdx.x * 256 + threadIdx.x;   // 20480 chunks of 8 elems
    int t    = idx >> 10;
    int kt   = (idx >> 7) & 7;
    int ks   = (idx >> 6) & 1;
    int quad = (idx >> 4) & 3;
    int l16  = idx & 15;
    int o  = t * 16 + l16;                       // weight row = output col
    int k0 = kt * 64 + ks * 32 + quad * 8;
    bf16x8 v;
    if (o < OUT_) {
        float4v f0 = *(const float4v*)(w + o * D_ + k0);
        float4v f1 = *(const float4v*)(w + o * D_ + k0 + 4);
        v[0]=(__bf16)f0[0]; v[1]=(__bf16)f0[1]; v[2]=(__bf16)f0[2]; v[3]=(__bf16)f0[3];
        v[4]=(__bf16)f1[0]; v[5]=(__bf16)f1[1]; v[6]=(__bf16)f1[2]; v[7]=(__bf16)f1[3];
    } else {
        #pragma unroll
        for (int j = 0; j < 8; ++j) v[j] = (__bf16)0.0f;
    }
    *(bf16x8*)(wpk + (size_t)idx * 8) = v;
}

// --- use = t1[:,0,:] ---
__global__ void use_copy_kernel(const float* __restrict__ t1, float* __restrict__ ou) {
    int idx = blockIdx.x * 256 + threadIdx.x;          // 8192 threads, float4 each
    int n = idx >> 7, dg = idx & 127;
    float4v v = *(const float4v*)(t1 + (size_t)n * L_ * D_ + dg * 4);
    *(float4v*)(ou + n * D_ + dg * 4) = v;
}

// --- fully fused, barrier-free: in-register span-means -> MFMA -> in-wave LN ---
// One wave per 16-row strip; wave owns all 20 col-tiles (full N).
__global__ __launch_bounds__(64) void enc_fused(
    const float* __restrict__ t1, const int* __restrict__ wseq,
    const __bf16* __restrict__ wpk, const float* __restrict__ b_lin,
    const float* __restrict__ gamma, const float* __restrict__ beta,
    float* __restrict__ out)
{
    const int lane = threadIdx.x;        // 0..63
    const int ln16 = lane & 15;
    const int quad = lane >> 4;
    const int m0   = blockIdx.x * 16;
    const int m    = m0 + ln16;          // the A-row this lane computes means for

    const int st  = min(wseq[2 * m],     L_ - 3);   // min(start, li-1), li = 1022
    const int en  = min(wseq[2 * m + 1], L_ - 2);   // min(end, li)
    const int cnt = en - st;
    const float inv_cnt = 1.0f / (float)cnt;
    const int nn = m / S_;
    const float* abase = t1 + ((size_t)nn * L_ + 1 + st) * D_ + quad * 8;

    float4v acc[NT_];
    #pragma unroll
    for (int t = 0; t < NT_; ++t) acc[t] = float4v{0.f, 0.f, 0.f, 0.f};

    for (int kt = 0; kt < 8; ++kt) {
        const int k0 = kt * 64;
        // ---- A: span-mean for this lane's (row, k-slice), straight from t1
        float4v s0a{0.f,0.f,0.f,0.f}, s0b{0.f,0.f,0.f,0.f};
        float4v s1a{0.f,0.f,0.f,0.f}, s1b{0.f,0.f,0.f,0.f};
        if (cnt == 8) {                  // fast path (true for this data)
            #pragma unroll
            for (int j = 0; j < 8; ++j) {
                const float* p = abase + j * D_ + k0;
                s0a += *(const float4v*)(p);
                s0b += *(const float4v*)(p + 4);
                s1a += *(const float4v*)(p + 32);
                s1b += *(const float4v*)(p + 36);
            }
        } else {
            for (int j = 0; j < cnt; ++j) {
                const float* p = abase + j * D_ + k0;
                s0a += *(const float4v*)(p);
                s0b += *(const float4v*)(p + 4);
                s1a += *(const float4v*)(p + 32);
                s1b += *(const float4v*)(p + 36);
            }
        }
        s0a *= inv_cnt; s0b *= inv_cnt; s1a *= inv_cnt; s1b *= inv_cnt;
        bf16x8 af0, af1;
        af0[0]=(__bf16)s0a[0]; af0[1]=(__bf16)s0a[1]; af0[2]=(__bf16)s0a[2]; af0[3]=(__bf16)s0a[3];
        af0[4]=(__bf16)s0b[0]; af0[5]=(__bf16)s0b[1]; af0[6]=(__bf16)s0b[2]; af0[7]=(__bf16)s0b[3];
        af1[0]=(__bf16)s1a[0]; af1[1]=(__bf16)s1a[1]; af1[2]=(__bf16)s1a[2]; af1[3]=(__bf16)s1a[3];
        af1[4]=(__bf16)s1b[0]; af1[5]=(__bf16)s1b[1]; af1[6]=(__bf16)s1b[2]; af1[7]=(__bf16)s1b[3];

        // ---- B from packed weights (coalesced 1 KB/wave, L2-hot), MFMA
        const __bf16* bp = wpk + ((size_t)kt * 128 + lane) * 8;
        #pragma unroll
        for (int t = 0; t < NT_; ++t) {
            bf16x8 b0 = *(const bf16x8*)(bp + t * 8192);         // ks=0
            acc[t] = __builtin_amdgcn_mfma_f32_16x16x32_bf16(af0, b0, acc[t], 0, 0, 0);
            bf16x8 b1 = *(const bf16x8*)(bp + t * 8192 + 512);   // ks=1
            acc[t] = __builtin_amdgcn_mfma_f32_16x16x32_bf16(af1, b1, acc[t], 0, 0, 0);
        }
    }

    // ---- epilogue, all in-wave. C layout: row = quad*4 + r, col = t*16 + ln16.
    // Padded cols (>=300) have zero weights and zero bias -> h == 0 -> contribute
    // nothing to sum/sumsq; divide by 300.
    float bl[NT_];
    #pragma unroll
    for (int t = 0; t < NT_; ++t) {
        int col = t * 16 + ln16;
        bl[t] = (col < OUT_) ? b_lin[col] : 0.0f;
    }
    float mu[4], rs[4];
    #pragma unroll
    for (int r = 0; r < 4; ++r) {
        float sum = 0.f, sq = 0.f;
        #pragma unroll
        for (int t = 0; t < NT_; ++t) {
            float h = acc[t][r] + bl[t];
            sum += h; sq += h * h;
        }
        #pragma unroll
        for (int off = 8; off > 0; off >>= 1) {   // reduce over ln16 within quad
            sum += __shfl_xor(sum, off);
            sq  += __shfl_xor(sq,  off);
        }
        mu[r] = sum * (1.0f / OUT_);
        float var = sq * (1.0f / OUT_) - mu[r] * mu[r];
        rs[r] = rsqrtf(var + EPS_);
    }
    #pragma unroll
    for (int t = 0; t < 19; ++t) {                // t=19 -> cols >= 304, all padded
        int col = t * 16 + ln16;
        if (col < OUT_) {
            float g = gamma[col], be = beta[col];
            #pragma unroll
            for (int r = 0; r < 4; ++r) {
                int gm = m0 + quad * 4 + r;
                float h = acc[t][r] + bl[t];
                out[(size_t)gm * OUT_ + col] = (h - mu[r]) * rs[r] * g + be;
            }
        }
    }
}

extern "C" void kernel_launch(void* const* d_in, const int* in_sizes, int n_in,
                              void* d_out, int out_size, void* d_ws, size_t ws_size,
                              hipStream_t stream) {
    const float* t1    = (const float*)d_in[0];
    const int*   wseq  = (const int*)d_in[1];   // word_seq (int32); d_in[2] mask unused
    const float* w_lin = (const float*)d_in[3];
    const float* b_lin = (const float*)d_in[4];
    const float* gamma = (const float*)d_in[5];
    const float* beta  = (const float*)d_in[6];
    float* out  = (float*)d_out;
    __bf16* wpk = (__bf16*)d_ws;                // 320*512*2 = 327680 B of scratch

    conv_w_pack<<<(NT_ * 1024) / 256, 256, 0, stream>>>(w_lin, wpk);
    enc_fused<<<NBLK, 64, 0, stream>>>(t1, wseq, wpk, b_lin, gamma, beta, out);
    use_copy_kernel<<<(N_ * D_ / 4) / 256, 256, 0, stream>>>(t1, out + (size_t)M_TOTAL * OUT_);
}

// Round 4
// 213.252 us; speedup vs baseline: 1.0356x; 1.0356x over previous
//
#include <hip/hip_runtime.h>
#include <hip/hip_bf16.h>
#include <stdint.h>

#define N_   64
#define L_   1024
#define D_   512
#define S_   127
#define OUT_ 300
#define NT_  20            // col-tiles of 16 -> 320 padded cols
#define OUTP (NT_*16)      // 320
#define EPS_ 1e-5f
#define M_TOTAL (N_*S_)    // 8128
#define NBLK (M_TOTAL/16)  // 508 blocks, 16 rows each
#define AST  520           // A LDS row stride (bf16): 1040B, 16B-aligned
#define HSTR 325           // epilogue h stride (floats): depads banks
#define PACK_BLOCKS 80     // NT_*1024/256
#define COPY_BLOCKS 32     // N_*D_/4/256

typedef __attribute__((ext_vector_type(4))) float  float4v;
typedef __attribute__((ext_vector_type(8))) __bf16 bf16x8;
typedef __attribute__((ext_vector_type(4))) __bf16 bf16x4;

// --- prep: pack w_lin f32->bf16 in MFMA B-fragment order, and copy use=t1[:,0,:] ---
// wpk elem layout: [t(20)][kt(8)][ks(2)][lane(64)][j(8)]  (lane = quad*16+ln16)
// B-frag for (t,kt,ks) at elem ((t*1024 + kt*128 + ks*64 + lane)*8): wave load = 1KB contiguous.
__global__ void prep_kernel(const float* __restrict__ w, __bf16* __restrict__ wpk,
                            const float* __restrict__ t1, float* __restrict__ ouse) {
    if (blockIdx.x < PACK_BLOCKS) {
        int idx = blockIdx.x * 256 + threadIdx.x;   // 20480 chunks of 8 elems
        int t    = idx >> 10;
        int kt   = (idx >> 7) & 7;
        int ks   = (idx >> 6) & 1;
        int quad = (idx >> 4) & 3;
        int l16  = idx & 15;
        int o  = t * 16 + l16;                       // weight row = output col
        int k0 = kt * 64 + ks * 32 + quad * 8;
        bf16x8 v;
        if (o < OUT_) {
            float4v f0 = *(const float4v*)(w + o * D_ + k0);
            float4v f1 = *(const float4v*)(w + o * D_ + k0 + 4);
            v[0]=(__bf16)f0[0]; v[1]=(__bf16)f0[1]; v[2]=(__bf16)f0[2]; v[3]=(__bf16)f0[3];
            v[4]=(__bf16)f1[0]; v[5]=(__bf16)f1[1]; v[6]=(__bf16)f1[2]; v[7]=(__bf16)f1[3];
        } else {
            #pragma unroll
            for (int j = 0; j < 8; ++j) v[j] = (__bf16)0.0f;
        }
        *(bf16x8*)(wpk + (size_t)idx * 8) = v;
    } else {
        int idx = (blockIdx.x - PACK_BLOCKS) * 256 + threadIdx.x;  // 8192 float4s
        int n = idx >> 7, dg = idx & 127;
        float4v v = *(const float4v*)(t1 + (size_t)n * L_ * D_ + dg * 4);
        *(float4v*)(ouse + n * D_ + dg * 4) = v;
    }
}

// --- fused: cooperative span-means -> LDS (one barrier) -> MFMA from global B -> LN ---
__global__ __launch_bounds__(256) void enc_fused(
    const float* __restrict__ t1, const int* __restrict__ wseq,
    const __bf16* __restrict__ wpk, const float* __restrict__ b_lin,
    const float* __restrict__ gamma, const float* __restrict__ beta,
    float* __restrict__ out)
{
    __shared__ __align__(16) char smem[16 * HSTR * 4];   // 20800B; A-tile (16x520 bf16) aliased
    __bf16* Alds = (__bf16*)smem;                        // [16][520]
    float*  hlds = (float*)smem;                         // [16][325]

    const int tid  = threadIdx.x;
    const int blk  = blockIdx.x;
    const int lane = tid & 63;
    const int wave = tid >> 6;
    const int quad = lane >> 4;
    const int ln16 = lane & 15;

    // ---- A-stage: full 16x512 mean tile, all 256 threads, one load burst
    {
        const int row = tid >> 4;          // 0..15
        const int kg  = tid & 15;          // float4 group base
        const int m   = blk * 16 + row;
        const int st  = min(wseq[2 * m],     L_ - 3);   // min(start, li-1), li=1022
        const int en  = min(wseq[2 * m + 1], L_ - 2);   // min(end, li)
        const int cnt = en - st;
        const float inv_cnt = 1.0f / (float)cnt;
        const int nn = m / S_;
        const float* base = t1 + ((size_t)nn * L_ + 1 + st) * D_ + kg * 4;
        #pragma unroll
        for (int c = 0; c < 8; ++c) {
            const int k0 = c * 64;
            float4v s = {0.f, 0.f, 0.f, 0.f};
            if (cnt == 8) {                // fast path (true for this data)
                #pragma unroll
                for (int j = 0; j < 8; ++j) s += *(const float4v*)(base + j * D_ + k0);
            } else {
                for (int j = 0; j < cnt; ++j) s += *(const float4v*)(base + j * D_ + k0);
            }
            s *= inv_cnt;
            bf16x4 a4;
            a4[0]=(__bf16)s[0]; a4[1]=(__bf16)s[1]; a4[2]=(__bf16)s[2]; a4[3]=(__bf16)s[3];
            *(bf16x4*)(Alds + row * AST + k0 + kg * 4) = a4;
        }
    }
    __syncthreads();

    // ---- GEMM: each wave owns 5 col-tiles, B-frags straight from L2-hot packed weights
    float4v acc[5];
    #pragma unroll
    for (int i = 0; i < 5; ++i) acc[i] = float4v{0.f, 0.f, 0.f, 0.f};
    const int t0 = wave * 5;

    #pragma unroll 2
    for (int kt = 0; kt < 8; ++kt) {
        bf16x8 af0 = *(const bf16x8*)(Alds + ln16 * AST + kt * 64 + quad * 8);
        bf16x8 af1 = *(const bf16x8*)(Alds + ln16 * AST + kt * 64 + 32 + quad * 8);
        const __bf16* bp = wpk + ((size_t)kt * 128 + lane) * 8;
        #pragma unroll
        for (int i = 0; i < 5; ++i) {
            const __bf16* bt = bp + (size_t)(t0 + i) * 8192;
            bf16x8 b0 = *(const bf16x8*)(bt);          // ks=0
            acc[i] = __builtin_amdgcn_mfma_f32_16x16x32_bf16(af0, b0, acc[i], 0, 0, 0);
            bf16x8 b1 = *(const bf16x8*)(bt + 512);    // ks=1
            acc[i] = __builtin_amdgcn_mfma_f32_16x16x32_bf16(af1, b1, acc[i], 0, 0, 0);
        }
    }
    __syncthreads();   // all A reads done; reuse LDS for h

    // ---- epilogue: h = acc + b_lin -> LDS (C layout: row = quad*4+r, col = t*16+ln16)
    #pragma unroll
    for (int i = 0; i < 5; ++i) {
        const int col = (t0 + i) * 16 + ln16;
        const float bl = (col < OUT_) ? b_lin[col] : 0.0f;
        #pragma unroll
        for (int r = 0; r < 4; ++r)
            hlds[(quad * 4 + r) * HSTR + col] = acc[i][r] + bl;
    }
    __syncthreads();

    // ---- LayerNorm over 300 cols; 16 threads per row
    const int r  = tid >> 4;
    const int c0 = tid & 15;
    float sum = 0.f, sq = 0.f;
    #pragma unroll
    for (int i = 0; i < 19; ++i) {
        int c = c0 + 16 * i;
        if (c < OUT_) { float v = hlds[r * HSTR + c]; sum += v; sq += v * v; }
    }
    #pragma unroll
    for (int off = 8; off > 0; off >>= 1) {
        sum += __shfl_xor(sum, off);
        sq  += __shfl_xor(sq,  off);
    }
    const float mu  = sum * (1.0f / OUT_);
    const float var = sq * (1.0f / OUT_) - mu * mu;
    const float rs  = rsqrtf(var + EPS_);
    float* orow = out + (size_t)(blk * 16 + r) * OUT_;
    #pragma unroll
    for (int i = 0; i < 19; ++i) {
        int c = c0 + 16 * i;
        if (c < OUT_) {
            float v = hlds[r * HSTR + c];
            orow[c] = (v - mu) * rs * gamma[c] + beta[c];
        }
    }
}

extern "C" void kernel_launch(void* const* d_in, const int* in_sizes, int n_in,
                              void* d_out, int out_size, void* d_ws, size_t ws_size,
                              hipStream_t stream) {
    const float* t1    = (const float*)d_in[0];
    const int*   wseq  = (const int*)d_in[1];   // word_seq (int32); d_in[2] mask unused
    const float* w_lin = (const float*)d_in[3];
    const float* b_lin = (const float*)d_in[4];
    const float* gamma = (const float*)d_in[5];
    const float* beta  = (const float*)d_in[6];
    float* out  = (float*)d_out;
    __bf16* wpk = (__bf16*)d_ws;                // 320*512*2 = 327680 B of scratch

    prep_kernel<<<PACK_BLOCKS + COPY_BLOCKS, 256, 0, stream>>>(
        w_lin, wpk, t1, out + (size_t)M_TOTAL * OUT_);
    enc_fused<<<NBLK, 256, 0, stream>>>(t1, wseq, wpk, b_lin, gamma, beta, out);
}